// Round 1
// baseline (6515.244 us; speedup 1.0000x reference)
//
#include <hip/hip_runtime.h>
#include <hip/hip_bf16.h>

#define BB 256
#define PP 48
#define NN 64
#define DE 64
#define HH 128
#define TT 5
#define NEPR 63
#define EPSBN 1e-5f

#define ET 32      // edge/node tile per pass
#define KT 16      // k-tile staged in LDS

// ---------------- batchnorm stats: scale/bias per channel ----------------
__global__ __launch_bounds__(256) void bn_stats_kernel(
    const float* __restrict__ x,
    const float* __restrict__ gamma,
    const float* __restrict__ beta,
    float* __restrict__ scale,
    float* __restrict__ bias)
{
    __shared__ float s_sum[256], s_sq[256];
    int p = blockIdx.x;
    int t = threadIdx.x;
    float sum = 0.f, sq = 0.f;
    for (int i = t; i < BB * NN; i += 256) {
        int b = i >> 6, n = i & 63;
        float v = x[b * PP * NN + p * NN + n];
        sum += v; sq += v * v;
    }
    s_sum[t] = sum; s_sq[t] = sq;
    __syncthreads();
    for (int off = 128; off > 0; off >>= 1) {
        if (t < off) { s_sum[t] += s_sum[t + off]; s_sq[t] += s_sq[t + off]; }
        __syncthreads();
    }
    if (t == 0) {
        float inv  = 1.f / (float)(BB * NN);
        float mean = s_sum[0] * inv;
        float var  = s_sq[0] * inv - mean * mean;
        float sc   = gamma[p] * rsqrtf(var + EPSBN);
        scale[p] = sc;
        bias[p]  = beta[p] - mean * sc;
    }
}

// ---------------- generic fused layer: Out = relu(W*In + init) ----------------
// In LDS [K][ET], Out LDS [OC][ET]; W global [OC][wstride], cols wcol0..wcol0+K
// thread tile: 4 channels x 4 elems; e-group fast (tid&7) so LDS banks spread.
template<int OC, int K>
__device__ __forceinline__ void layer_fc(
    const float* __restrict__ W, int wstride, int wcol0,
    const float* __restrict__ initv,   // [OC], generic ptr (global bias or LDS)
    const float* __restrict__ inLds,
    float* __restrict__ outLds,
    float* __restrict__ wtLds,         // KT*OC floats
    int t)
{
    constexpr int TILES = 2 * OC;            // (OC/4)*(ET/4)
    constexpr int NT = (TILES + 255) / 256;  // 1 or 2
    float acc[NT][16];
#pragma unroll
    for (int n = 0; n < NT; n++)
#pragma unroll
        for (int i = 0; i < 16; i++) acc[n][i] = 0.f;

    for (int k0 = 0; k0 < K; k0 += KT) {
        __syncthreads();   // protect wtLds reuse
#pragma unroll
        for (int ii = 0; ii < (KT * OC) / 256; ii++) {
            int i  = t + ii * 256;
            int ch = i & (OC - 1);
            int kk = i / OC;
            wtLds[i] = W[ch * wstride + wcol0 + k0 + kk];  // wt[kk][ch]
        }
        __syncthreads();
#pragma unroll
        for (int kk = 0; kk < KT; kk++) {
#pragma unroll
            for (int n = 0; n < NT; n++) {
                int tid = t + 256 * n;
                if (tid < TILES) {
                    int e0  = (tid & 7) << 2;
                    int ch0 = (tid >> 3) << 2;
                    float4 wv = *(const float4*)&wtLds[kk * OC + ch0];
                    float4 av = *(const float4*)&inLds[(k0 + kk) * ET + e0];
                    acc[n][0]  += wv.x * av.x; acc[n][1]  += wv.x * av.y;
                    acc[n][2]  += wv.x * av.z; acc[n][3]  += wv.x * av.w;
                    acc[n][4]  += wv.y * av.x; acc[n][5]  += wv.y * av.y;
                    acc[n][6]  += wv.y * av.z; acc[n][7]  += wv.y * av.w;
                    acc[n][8]  += wv.z * av.x; acc[n][9]  += wv.z * av.y;
                    acc[n][10] += wv.z * av.z; acc[n][11] += wv.z * av.w;
                    acc[n][12] += wv.w * av.x; acc[n][13] += wv.w * av.y;
                    acc[n][14] += wv.w * av.z; acc[n][15] += wv.w * av.w;
                }
            }
        }
    }
#pragma unroll
    for (int n = 0; n < NT; n++) {
        int tid = t + 256 * n;
        if (tid < TILES) {
            int e0  = (tid & 7) << 2;
            int ch0 = (tid >> 3) << 2;
#pragma unroll
            for (int i = 0; i < 4; i++) {
                float bi = initv[ch0 + i];
                float4 o;
                o.x = fmaxf(acc[n][4 * i + 0] + bi, 0.f);
                o.y = fmaxf(acc[n][4 * i + 1] + bi, 0.f);
                o.z = fmaxf(acc[n][4 * i + 2] + bi, 0.f);
                o.w = fmaxf(acc[n][4 * i + 3] + bi, 0.f);
                *(float4*)&outLds[(ch0 + i) * ET + e0] = o;
            }
        }
    }
}

// ---------------- edge MLP + scatter-add (one block per (receiver, batch)) ----
__global__ __launch_bounds__(256) void edge_kernel(
    const float* __restrict__ x,
    const int*   __restrict__ senders,
    const float* __restrict__ scale,
    const float* __restrict__ bias,
    const float* __restrict__ fr1_w, const float* __restrict__ fr1_b,
    const float* __restrict__ fr2_w, const float* __restrict__ fr2_b,
    const float* __restrict__ fr3_w, const float* __restrict__ fr3_b,
    float* __restrict__ ebar)   // [B][DE][NN]
{
    __shared__ float xnT[NN * PP];      // [n][p]
    __shared__ float wt[KT * 256];
    __shared__ float rcvinit[256];
    __shared__ float in0[PP * ET];      // [p][e] sender features
    __shared__ float act1[256 * ET];
    __shared__ float act2[128 * ET];
    __shared__ float act3[64 * ET];
    __shared__ int   ssub[64];

    int r = blockIdx.x;
    int b = blockIdx.y;
    int t = threadIdx.x;

    // normalized node features for this batch, transposed [n][p]
#pragma unroll
    for (int ii = 0; ii < (NN * PP) / 256; ii++) {
        int i = t + ii * 256;
        int p = i >> 6;
        int n = i & 63;
        xnT[n * PP + p] = x[b * PP * NN + i] * scale[p] + bias[p];
    }
    if (t < 64) ssub[t] = (t < NEPR) ? senders[r * NEPR + t] : 0;
    __syncthreads();

    // receiver half of layer 1 (constant over the 63 edges) + bias
    {
        float a = fr1_b[t];
        const float* wrow = fr1_w + t * 96;   // cols 0..47 = receiver features
        for (int p = 0; p < PP; p++) a += wrow[p] * xnT[r * PP + p];
        rcvinit[t] = a;
    }

    float ebsum = 0.f;   // thread t<64 accumulates Ebar[b][t][r]

    for (int pass = 0; pass < 2; pass++) {
        int ebase = pass * ET;
        // build sender inputs in0[p][e]
#pragma unroll
        for (int ii = 0; ii < (PP * ET) / 256; ii++) {
            int i = t + ii * 256;
            int e = i & 31;
            int p = i >> 5;
            int s = ssub[ebase + e];
            in0[p * ET + e] = xnT[s * PP + p];
        }
        layer_fc<256, PP>(fr1_w, 96, PP, rcvinit, in0, act1, wt, t);   // sender cols 48..95
        layer_fc<128, 256>(fr2_w, 256, 0, fr2_b, act1, act2, wt, t);
        layer_fc<64, 128>(fr3_w, 128, 0, fr3_b, act2, act3, wt, t);
        __syncthreads();
        if (t < 64) {
            int nvalid = NEPR - ebase;            // 63 -> 32 (cap) / 31
            if (nvalid > ET) nvalid = ET;
            for (int j = 0; j < ET; j++) {
                int e = (t + j) & 31;             // rotate to avoid bank camping
                if (e < nvalid) ebsum += act3[t * ET + e];
            }
        }
    }
    if (t < 64) ebar[b * DE * NN + t * NN + r] = ebsum;
}

// ---------------- node MLP + node-sum + final FCs (one block per batch) -------
__global__ __launch_bounds__(256) void node_kernel(
    const float* __restrict__ x,
    const float* __restrict__ scale, const float* __restrict__ bias,
    const float* __restrict__ ebar,
    const float* __restrict__ fo1_w, const float* __restrict__ fo1_b,
    const float* __restrict__ fo2_w, const float* __restrict__ fo2_b,
    const float* __restrict__ fo3_w, const float* __restrict__ fo3_b,
    const float* __restrict__ fc1_w, const float* __restrict__ fc1_b,
    const float* __restrict__ fc2_w, const float* __restrict__ fc2_b,
    const float* __restrict__ fc3_w, const float* __restrict__ fc3_b,
    float* __restrict__ out)
{
    __shared__ float act0[112 * ET];
    __shared__ float act1[256 * ET];
    __shared__ float act2[128 * ET];
    __shared__ float act3[64 * ET];
    __shared__ float wt[KT * 256];
    __shared__ float red[64];
    __shared__ float h1[32], h2[16];

    int b = blockIdx.x;
    int t = threadIdx.x;
    float nsum = 0.f;

    for (int pass = 0; pass < 2; pass++) {
        int n0 = pass * ET;
        __syncthreads();
        // xn rows 0..47
#pragma unroll
        for (int ii = 0; ii < (PP * ET) / 256; ii++) {
            int i = t + ii * 256;
            int e = i & 31, p = i >> 5;
            act0[p * ET + e] = x[b * PP * NN + p * NN + n0 + e] * scale[p] + bias[p];
        }
        // ebar rows 48..111
#pragma unroll
        for (int ii = 0; ii < (DE * ET) / 256; ii++) {
            int i = t + ii * 256;
            int e = i & 31, d = i >> 5;
            act0[(PP + d) * ET + e] = ebar[b * DE * NN + d * NN + n0 + e];
        }
        layer_fc<256, 112>(fo1_w, 112, 0, fo1_b, act0, act1, wt, t);
        layer_fc<128, 256>(fo2_w, 256, 0, fo2_b, act1, act2, wt, t);
        layer_fc<64, 128>(fo3_w, 128, 0, fo3_b, act2, act3, wt, t);
        __syncthreads();
        if (t < 64) {
            for (int j = 0; j < ET; j++) {
                int e = (t + j) & 31;
                nsum += act3[t * ET + e];
            }
        }
    }
    if (t < 64) red[t] = nsum;
    __syncthreads();
    if (t < 25) {
        float a = fc1_b[t];
        for (int k = 0; k < 64; k++) a += fc1_w[t * 64 + k] * red[k];
        h1[t] = a;
    }
    __syncthreads();
    if (t < 15) {
        float a = fc2_b[t];
        for (int k = 0; k < 25; k++) a += fc2_w[t * 25 + k] * h1[k];
        h2[t] = a;
    }
    __syncthreads();
    if (t < TT) {
        float a = fc3_b[t];
        for (int k = 0; k < 15; k++) a += fc3_w[t * 15 + k] * h2[k];
        out[b * TT + t] = a;
    }
}

extern "C" void kernel_launch(void* const* d_in, const int* in_sizes, int n_in,
                              void* d_out, int out_size, void* d_ws, size_t ws_size,
                              hipStream_t stream)
{
    const float* x        = (const float*)d_in[0];
    const int*   senders  = (const int*)  d_in[2];
    const float* bn_gamma = (const float*)d_in[3];
    const float* bn_beta  = (const float*)d_in[4];
    const float* fr1_w = (const float*)d_in[5];
    const float* fr1_b = (const float*)d_in[6];
    const float* fr2_w = (const float*)d_in[7];
    const float* fr2_b = (const float*)d_in[8];
    const float* fr3_w = (const float*)d_in[9];
    const float* fr3_b = (const float*)d_in[10];
    const float* fo1_w = (const float*)d_in[11];
    const float* fo1_b = (const float*)d_in[12];
    const float* fo2_w = (const float*)d_in[13];
    const float* fo2_b = (const float*)d_in[14];
    const float* fo3_w = (const float*)d_in[15];
    const float* fo3_b = (const float*)d_in[16];
    const float* fc1_w = (const float*)d_in[17];
    const float* fc1_b = (const float*)d_in[18];
    const float* fc2_w = (const float*)d_in[19];
    const float* fc2_b = (const float*)d_in[20];
    const float* fc3_w = (const float*)d_in[21];
    const float* fc3_b = (const float*)d_in[22];

    float* ws    = (float*)d_ws;
    float* scale = ws;          // 48
    float* bias  = ws + 64;     // 48
    float* ebar  = ws + 128;    // B*DE*NN = 1,048,576 floats
    float* out   = (float*)d_out;

    bn_stats_kernel<<<dim3(PP), dim3(256), 0, stream>>>(x, bn_gamma, bn_beta, scale, bias);
    edge_kernel<<<dim3(NN, BB), dim3(256), 0, stream>>>(
        x, senders, scale, bias,
        fr1_w, fr1_b, fr2_w, fr2_b, fr3_w, fr3_b, ebar);
    node_kernel<<<dim3(BB), dim3(256), 0, stream>>>(
        x, scale, bias, ebar,
        fo1_w, fo1_b, fo2_w, fo2_b, fo3_w, fo3_b,
        fc1_w, fc1_b, fc2_w, fc2_b, fc3_w, fc3_b, out);
}

// Round 2
// 463.820 us; speedup vs baseline: 14.0469x; 14.0469x over previous
//
#include <hip/hip_runtime.h>

#define BB 256
#define PP 48
#define NN 64
#define EPSBN 1e-5f

typedef __attribute__((ext_vector_type(8))) short bf16x8;
typedef __attribute__((ext_vector_type(4))) float f32x4;

// ---- LDS region offsets (ushort elements) ----
#define W1O 0        // [256][64]   fr1 sender half (bf16)   | phase-N: act1N [64][256]
#define W2O 16384    // [128][256]  fr2                      | phase-N: fo1 [256][128] then fo2 [128][256]
#define W3O 49152    // [64][128]   fr3                      | phase-N: fo3 [64][128]
#define A0O 57344    // [64][128]   node input: [ebar(0..63), xn(64..111), 0(112..127)]
#define A1O 65536    // [32][256]   edge act1                | phase-N: act2N [64][128]
#define A2O 73728    // [32][128]   edge act2
#define LDSE 77824   // 155648 B

__device__ __forceinline__ ushort f2b(float f) {
    union { float f; unsigned u; } a; a.f = f;
    unsigned u = a.u + 0x7FFFu + ((a.u >> 16) & 1u);
    return (ushort)(u >> 16);
}
__device__ __forceinline__ float b2f(ushort s) {
    union { unsigned u; float f; } a; a.u = ((unsigned)s) << 16;
    return a.f;
}
// swizzled scalar index: 16B-chunk XOR'd by row&7 (banks spread, <=2-way)
__device__ __forceinline__ int sidx(int row, int k, int kpad) {
    return row * kpad + ((((k >> 3) ^ (row & 7)) << 3) | (k & 7));
}
// fragment load: 8 consecutive bf16 at (row, k..k+7), k multiple of 8
__device__ __forceinline__ bf16x8 ldfrag(const ushort* buf, int row, int k, int kpad) {
    return *(const bf16x8*)(buf + row * kpad + (((k >> 3) ^ (row & 7)) << 3));
}
__device__ __forceinline__ f32x4 MFMA(bf16x8 a, bf16x8 b, f32x4 c) {
    return __builtin_amdgcn_mfma_f32_16x16x32_bf16(a, b, c, 0, 0, 0);
}
// epilogue store: relu(acc+bias) -> 4 bf16 at (row, c0..c0+3), c0 multiple of 4
__device__ __forceinline__ void stAct(ushort* buf, int row, int c0, int kpad, f32x4 a, float4 bi) {
    ushort4 o;
    o.x = f2b(fmaxf(a[0] + bi.x, 0.f));
    o.y = f2b(fmaxf(a[1] + bi.y, 0.f));
    o.z = f2b(fmaxf(a[2] + bi.z, 0.f));
    o.w = f2b(fmaxf(a[3] + bi.w, 0.f));
    *(ushort4*)(buf + row * kpad + ((((c0 >> 3) ^ (row & 7)) << 3) | (c0 & 7))) = o;
}

// ---------------- batchnorm stats ----------------
__global__ __launch_bounds__(256) void bn_stats_kernel(
    const float* __restrict__ x, const float* __restrict__ gamma,
    const float* __restrict__ beta, float* __restrict__ scale, float* __restrict__ bias)
{
    __shared__ float s_sum[256], s_sq[256];
    int p = blockIdx.x, t = threadIdx.x;
    float sum = 0.f, sq = 0.f;
    for (int i = t; i < BB * NN; i += 256) {
        int b = i >> 6, n = i & 63;
        float v = x[b * PP * NN + p * NN + n];
        sum += v; sq += v * v;
    }
    s_sum[t] = sum; s_sq[t] = sq;
    __syncthreads();
    for (int off = 128; off > 0; off >>= 1) {
        if (t < off) { s_sum[t] += s_sum[t + off]; s_sq[t] += s_sq[t + off]; }
        __syncthreads();
    }
    if (t == 0) {
        float inv = 1.f / (float)(BB * NN);
        float mean = s_sum[0] * inv;
        float var  = s_sq[0] * inv - mean * mean;
        float sc   = gamma[p] * rsqrtf(var + EPSBN);
        scale[p] = sc;
        bias[p]  = beta[p] - mean * sc;
    }
}

// ---------------- mega kernel: one block per batch ----------------
__global__ __launch_bounds__(256, 1) void meg_kernel(
    const float* __restrict__ x,
    const int*   __restrict__ senders,
    const float* __restrict__ scl, const float* __restrict__ bia,
    const float* __restrict__ fr1_w, const float* __restrict__ fr1_b,
    const float* __restrict__ fr2_w, const float* __restrict__ fr2_b,
    const float* __restrict__ fr3_w, const float* __restrict__ fr3_b,
    const float* __restrict__ fo1_w, const float* __restrict__ fo1_b,
    const float* __restrict__ fo2_w, const float* __restrict__ fo2_b,
    const float* __restrict__ fo3_w, const float* __restrict__ fo3_b,
    const float* __restrict__ fc1_w, const float* __restrict__ fc1_b,
    const float* __restrict__ fc2_w, const float* __restrict__ fc2_b,
    const float* __restrict__ fc3_w, const float* __restrict__ fc3_b,
    float* __restrict__ out)
{
    __shared__ __align__(16) ushort L[LDSE];
    __shared__ float rcvinit[256], biasA[256], biasB[64], biasC[128];
    __shared__ float red[64], h1[32], h2[16];
    __shared__ int ssub[64];

    int b = blockIdx.x, t = threadIdx.x;
    int w = t >> 6;          // wave 0..3
    int l = t & 63;          // lane
    int lx = l & 15;         // n / m index within tile
    int lq = l >> 4;         // quad 0..3

    // ---- stage act0: cols 0..63 ebar (filled later), 64..111 xn, 112..127 zero
    for (int i = t; i < 8192; i += 256) {
        int row = i >> 7, k = i & 127;
        float v = 0.f;
        if (k >= 64 && k < 112) {
            int p = k - 64;
            v = x[b * PP * NN + p * NN + row] * scl[p] + bia[p];
        }
        L[A0O + sidx(row, k, 128)] = f2b(v);
    }
    // ---- stage fr1 sender half [256][64] (cols 48..63 zero)
    for (int i = t; i < 16384; i += 256) {
        int ch = i >> 6, k = i & 63;
        float v = (k < PP) ? fr1_w[ch * 96 + PP + k] : 0.f;
        L[W1O + sidx(ch, k, 64)] = f2b(v);
    }
    // ---- stage fr2 [128][256]
    for (int i = t; i < 32768; i += 256) {
        int ch = i >> 8, k = i & 255;
        L[W2O + sidx(ch, k, 256)] = f2b(fr2_w[i]);
    }
    // ---- stage fr3 [64][128]
    for (int i = t; i < 8192; i += 256) {
        int ch = i >> 7, k = i & 127;
        L[W3O + sidx(ch, k, 128)] = f2b(fr3_w[i]);
    }
    if (t < 128) biasA[t] = fr2_b[t];
    if (t < 64)  biasB[t] = fr3_b[t];
    __syncthreads();

    // =================== phase E: receivers ===================
    for (int r = 0; r < NN; ++r) {
        if (t < 64) ssub[t] = (t < 63) ? senders[r * 63 + t] : 0;
        // receiver half of layer 1 (+bias), ch = t
        {
            float s = fr1_b[t];
            const float4* wr = (const float4*)(fr1_w + t * 96);
#pragma unroll
            for (int p4 = 0; p4 < 12; ++p4) {
                float4 wv = wr[p4];
                int p = 64 + p4 * 4;
                s += wv.x * b2f(L[A0O + sidx(r, p + 0, 128)]);
                s += wv.y * b2f(L[A0O + sidx(r, p + 1, 128)]);
                s += wv.z * b2f(L[A0O + sidx(r, p + 2, 128)]);
                s += wv.w * b2f(L[A0O + sidx(r, p + 3, 128)]);
            }
            rcvinit[t] = s;
        }
        __syncthreads();

        float es0 = 0.f, es1 = 0.f, es2 = 0.f, es3 = 0.f;
#pragma unroll
        for (int pass = 0; pass < 2; ++pass) {
            int e0 = pass * 32;
            // ---- L1: M=256 (wave: m-tiles 4w..4w+3), N=32, K=64 (48 real)
            int srow0 = ssub[e0 + lx];
            int srow1 = ssub[e0 + 16 + lx];
            bf16x8 Bf[2][2];
#pragma unroll
            for (int ks = 0; ks < 2; ++ks) {
                Bf[0][ks] = ldfrag(L + A0O, srow0, 64 + ks * 32 + lq * 8, 128);
                Bf[1][ks] = ldfrag(L + A0O, srow1, 64 + ks * 32 + lq * 8, 128);
            }
            f32x4 acc1[4][2];
#pragma unroll
            for (int j = 0; j < 4; ++j) {
                int m0 = (4 * w + j) * 16;
                bf16x8 A0f = ldfrag(L + W1O, m0 + lx, 0 + lq * 8, 64);
                bf16x8 A1f = ldfrag(L + W1O, m0 + lx, 32 + lq * 8, 64);
#pragma unroll
                for (int nt = 0; nt < 2; ++nt) {
                    f32x4 a = {0.f, 0.f, 0.f, 0.f};
                    a = MFMA(A0f, Bf[nt][0], a);
                    a = MFMA(A1f, Bf[nt][1], a);
                    acc1[j][nt] = a;
                }
            }
#pragma unroll
            for (int j = 0; j < 4; ++j) {
                int ch0 = (4 * w + j) * 16 + lq * 4;
                float4 rv = *(const float4*)&rcvinit[ch0];
#pragma unroll
                for (int nt = 0; nt < 2; ++nt)
                    stAct(L + A1O, nt * 16 + lx, ch0, 256, acc1[j][nt], rv);
            }
            __syncthreads();

            // ---- L2: M=128 (wave: m-tiles 2w,2w+1), N=32, K=256
            f32x4 acc2[2][2];
#pragma unroll
            for (int j = 0; j < 2; ++j)
#pragma unroll
                for (int nt = 0; nt < 2; ++nt) acc2[j][nt] = (f32x4){0.f, 0.f, 0.f, 0.f};
#pragma unroll
            for (int ks = 0; ks < 8; ++ks) {
                bf16x8 B0 = ldfrag(L + A1O, lx,      ks * 32 + lq * 8, 256);
                bf16x8 B1 = ldfrag(L + A1O, 16 + lx, ks * 32 + lq * 8, 256);
                bf16x8 Aa = ldfrag(L + W2O, (2 * w + 0) * 16 + lx, ks * 32 + lq * 8, 256);
                bf16x8 Ab = ldfrag(L + W2O, (2 * w + 1) * 16 + lx, ks * 32 + lq * 8, 256);
                acc2[0][0] = MFMA(Aa, B0, acc2[0][0]);
                acc2[0][1] = MFMA(Aa, B1, acc2[0][1]);
                acc2[1][0] = MFMA(Ab, B0, acc2[1][0]);
                acc2[1][1] = MFMA(Ab, B1, acc2[1][1]);
            }
#pragma unroll
            for (int j = 0; j < 2; ++j) {
                int ch0 = (2 * w + j) * 16 + lq * 4;
                float4 bi = *(const float4*)&biasA[ch0];
                stAct(L + A2O, lx,      ch0, 128, acc2[j][0], bi);
                stAct(L + A2O, 16 + lx, ch0, 128, acc2[j][1], bi);
            }
            __syncthreads();

            // ---- L3: M=64 (wave: m-tile w), N=32, K=128
            f32x4 acc3[2];
            acc3[0] = (f32x4){0.f, 0.f, 0.f, 0.f};
            acc3[1] = (f32x4){0.f, 0.f, 0.f, 0.f};
#pragma unroll
            for (int ks = 0; ks < 4; ++ks) {
                bf16x8 Aw = ldfrag(L + W3O, 16 * w + lx, ks * 32 + lq * 8, 128);
                bf16x8 B0 = ldfrag(L + A2O, lx,      ks * 32 + lq * 8, 128);
                bf16x8 B1 = ldfrag(L + A2O, 16 + lx, ks * 32 + lq * 8, 128);
                acc3[0] = MFMA(Aw, B0, acc3[0]);
                acc3[1] = MFMA(Aw, B1, acc3[1]);
            }
            float4 b3 = *(const float4*)&biasB[16 * w + lq * 4];
            float m1 = (pass == 1 && lx == 15) ? 0.f : 1.f;  // mask pad edge 63
            es0 += fmaxf(acc3[0][0] + b3.x, 0.f) + m1 * fmaxf(acc3[1][0] + b3.x, 0.f);
            es1 += fmaxf(acc3[0][1] + b3.y, 0.f) + m1 * fmaxf(acc3[1][1] + b3.y, 0.f);
            es2 += fmaxf(acc3[0][2] + b3.z, 0.f) + m1 * fmaxf(acc3[1][2] + b3.z, 0.f);
            es3 += fmaxf(acc3[0][3] + b3.w, 0.f) + m1 * fmaxf(acc3[1][3] + b3.w, 0.f);
        } // pass

        // reduce over the 16 edge-lanes, deposit ebar[ch][r] into act0[r][ch]
#pragma unroll
        for (int off = 8; off >= 1; off >>= 1) {
            es0 += __shfl_xor(es0, off, 16);
            es1 += __shfl_xor(es1, off, 16);
            es2 += __shfl_xor(es2, off, 16);
            es3 += __shfl_xor(es3, off, 16);
        }
        if (lx == 0) {
            int ch0 = 16 * w + lq * 4;
            ushort4 o;
            o.x = f2b(es0); o.y = f2b(es1); o.z = f2b(es2); o.w = f2b(es3);
            *(ushort4*)(L + A0O + r * 128 + ((((ch0 >> 3) ^ (r & 7)) << 3) | (ch0 & 7))) = o;
        }
        // no barrier needed: next receiver's ssub/rcvinit writes are fenced by
        // the post-rcvinit barrier; ebar cols 0..63 unread in phase E.
    }
    __syncthreads();   // all ebar writes visible

    // =================== phase N: node MLP ===================
    // restage fo1 -> W2 [256][128], cols permuted to [ebar(64), xn(48), 0(16)]
    for (int i = t; i < 32768; i += 256) {
        int ch = i >> 7, k = i & 127;
        float v = 0.f;
        if (k < 64)       v = fo1_w[ch * 112 + PP + k];
        else if (k < 112) v = fo1_w[ch * 112 + (k - 64)];
        L[W2O + sidx(ch, k, 128)] = f2b(v);
    }
    // restage fo3 -> W3 [64][128]
    for (int i = t; i < 8192; i += 256) {
        int ch = i >> 7, k = i & 127;
        L[W3O + sidx(ch, k, 128)] = f2b(fo3_w[i]);
    }
    biasA[t] = fo1_b[t];
    if (t < 128) biasC[t] = fo2_b[t];
    if (t < 64)  biasB[t] = fo3_b[t];
    __syncthreads();

    // ---- L1N: M=256 (wave: m-tiles 4w..4w+3), N=64, K=128 -> act1N @ W1O [64][256]
    {
        f32x4 accN[4][4];
#pragma unroll
        for (int j = 0; j < 4; ++j)
#pragma unroll
            for (int nt = 0; nt < 4; ++nt) accN[j][nt] = (f32x4){0.f, 0.f, 0.f, 0.f};
#pragma unroll
        for (int ks = 0; ks < 4; ++ks) {
            bf16x8 Bf[4];
#pragma unroll
            for (int nt = 0; nt < 4; ++nt)
                Bf[nt] = ldfrag(L + A0O, nt * 16 + lx, ks * 32 + lq * 8, 128);
#pragma unroll
            for (int j = 0; j < 4; ++j) {
                bf16x8 Af = ldfrag(L + W2O, (4 * w + j) * 16 + lx, ks * 32 + lq * 8, 128);
#pragma unroll
                for (int nt = 0; nt < 4; ++nt)
                    accN[j][nt] = MFMA(Af, Bf[nt], accN[j][nt]);
            }
        }
        __syncthreads();   // W1O (fr1) reads finished in phase E; safe to overwrite
#pragma unroll
        for (int j = 0; j < 4; ++j) {
            int ch0 = (4 * w + j) * 16 + lq * 4;
            float4 bi = *(const float4*)&biasA[ch0];
#pragma unroll
            for (int nt = 0; nt < 4; ++nt)
                stAct(L + W1O, nt * 16 + lx, ch0, 256, accN[j][nt], bi);
        }
    }
    __syncthreads();
    // restage fo2 -> W2 [128][256]
    for (int i = t; i < 32768; i += 256) {
        int ch = i >> 8, k = i & 255;
        L[W2O + sidx(ch, k, 256)] = f2b(fo2_w[i]);
    }
    __syncthreads();

    // ---- L2N: M=128 (wave: m-tiles 2w,2w+1), N=64, K=256 -> act2N @ A1O [64][128]
    {
        f32x4 acc2N[2][4];
#pragma unroll
        for (int j = 0; j < 2; ++j)
#pragma unroll
            for (int nt = 0; nt < 4; ++nt) acc2N[j][nt] = (f32x4){0.f, 0.f, 0.f, 0.f};
#pragma unroll
        for (int ks = 0; ks < 8; ++ks) {
            bf16x8 Bf[4];
#pragma unroll
            for (int nt = 0; nt < 4; ++nt)
                Bf[nt] = ldfrag(L + W1O, nt * 16 + lx, ks * 32 + lq * 8, 256);
#pragma unroll
            for (int j = 0; j < 2; ++j) {
                bf16x8 Af = ldfrag(L + W2O, (2 * w + j) * 16 + lx, ks * 32 + lq * 8, 256);
#pragma unroll
                for (int nt = 0; nt < 4; ++nt)
                    acc2N[j][nt] = MFMA(Af, Bf[nt], acc2N[j][nt]);
            }
        }
        __syncthreads();   // A1O reads from phase E done
#pragma unroll
        for (int j = 0; j < 2; ++j) {
            int ch0 = (2 * w + j) * 16 + lq * 4;
            float4 bi = *(const float4*)&biasC[ch0];
#pragma unroll
            for (int nt = 0; nt < 4; ++nt)
                stAct(L + A1O, nt * 16 + lx, ch0, 128, acc2N[j][nt], bi);
        }
    }
    __syncthreads();

    // ---- L3N: M=64 (wave: m-tile w), N=64, K=128; relu+bias then sum over nodes
    {
        f32x4 acc3N[4];
#pragma unroll
        for (int nt = 0; nt < 4; ++nt) acc3N[nt] = (f32x4){0.f, 0.f, 0.f, 0.f};
#pragma unroll
        for (int ks = 0; ks < 4; ++ks) {
            bf16x8 Af = ldfrag(L + W3O, 16 * w + lx, ks * 32 + lq * 8, 128);
#pragma unroll
            for (int nt = 0; nt < 4; ++nt) {
                bf16x8 Bf = ldfrag(L + A1O, nt * 16 + lx, ks * 32 + lq * 8, 128);
                acc3N[nt] = MFMA(Af, Bf, acc3N[nt]);
            }
        }
        float4 b3 = *(const float4*)&biasB[16 * w + lq * 4];
        float o0 = 0.f, o1 = 0.f, o2 = 0.f, o3 = 0.f;
#pragma unroll
        for (int nt = 0; nt < 4; ++nt) {
            o0 += fmaxf(acc3N[nt][0] + b3.x, 0.f);
            o1 += fmaxf(acc3N[nt][1] + b3.y, 0.f);
            o2 += fmaxf(acc3N[nt][2] + b3.z, 0.f);
            o3 += fmaxf(acc3N[nt][3] + b3.w, 0.f);
        }
#pragma unroll
        for (int off = 8; off >= 1; off >>= 1) {
            o0 += __shfl_xor(o0, off, 16);
            o1 += __shfl_xor(o1, off, 16);
            o2 += __shfl_xor(o2, off, 16);
            o3 += __shfl_xor(o3, off, 16);
        }
        if (lx == 0) {
            int ch0 = 16 * w + lq * 4;
            *(float4*)&red[ch0] = make_float4(o0, o1, o2, o3);
        }
    }
    __syncthreads();

    // ---- final FCs (fp32)
    if (t < 25) {
        float s = fc1_b[t];
        for (int k = 0; k < 64; ++k) s += fc1_w[t * 64 + k] * red[k];
        h1[t] = s;
    }
    __syncthreads();
    if (t < 15) {
        float s = fc2_b[t];
        for (int k = 0; k < 25; ++k) s += fc2_w[t * 25 + k] * h1[k];
        h2[t] = s;
    }
    __syncthreads();
    if (t < 5) {
        float s = fc3_b[t];
        for (int k = 0; k < 15; ++k) s += fc3_w[t * 15 + k] * h2[k];
        out[b * 5 + t] = s;
    }
}

extern "C" void kernel_launch(void* const* d_in, const int* in_sizes, int n_in,
                              void* d_out, int out_size, void* d_ws, size_t ws_size,
                              hipStream_t stream)
{
    const float* x        = (const float*)d_in[0];
    const int*   senders  = (const int*)  d_in[2];
    const float* bn_gamma = (const float*)d_in[3];
    const float* bn_beta  = (const float*)d_in[4];
    const float* fr1_w = (const float*)d_in[5];
    const float* fr1_b = (const float*)d_in[6];
    const float* fr2_w = (const float*)d_in[7];
    const float* fr2_b = (const float*)d_in[8];
    const float* fr3_w = (const float*)d_in[9];
    const float* fr3_b = (const float*)d_in[10];
    const float* fo1_w = (const float*)d_in[11];
    const float* fo1_b = (const float*)d_in[12];
    const float* fo2_w = (const float*)d_in[13];
    const float* fo2_b = (const float*)d_in[14];
    const float* fo3_w = (const float*)d_in[15];
    const float* fo3_b = (const float*)d_in[16];
    const float* fc1_w = (const float*)d_in[17];
    const float* fc1_b = (const float*)d_in[18];
    const float* fc2_w = (const float*)d_in[19];
    const float* fc2_b = (const float*)d_in[20];
    const float* fc3_w = (const float*)d_in[21];
    const float* fc3_b = (const float*)d_in[22];

    float* ws    = (float*)d_ws;
    float* scale = ws;
    float* bias  = ws + 64;
    float* out   = (float*)d_out;

    bn_stats_kernel<<<dim3(PP), dim3(256), 0, stream>>>(x, bn_gamma, bn_beta, scale, bias);
    meg_kernel<<<dim3(BB), dim3(256), 0, stream>>>(
        x, senders, scale, bias,
        fr1_w, fr1_b, fr2_w, fr2_b, fr3_w, fr3_b,
        fo1_w, fo1_b, fo2_w, fo2_b, fo3_w, fo3_b,
        fc1_w, fc1_b, fc2_w, fc2_b, fc3_w, fc3_b, out);
}